// Round 8
// baseline (969.193 us; speedup 1.0000x reference)
//
#include <hip/hip_runtime.h>

typedef __attribute__((ext_vector_type(4))) float f32x4;
typedef __attribute__((ext_vector_type(4))) unsigned int u32x4;

__device__ __forceinline__ unsigned short f2bf(float f){
    unsigned u = __float_as_uint(f);
    u += 0x7FFFu + ((u >> 16) & 1u);   // RNE
    return (unsigned short)(u >> 16);
}
__device__ __forceinline__ unsigned pack2(float lo, float hi){
    return (unsigned)f2bf(lo) | ((unsigned)f2bf(hi) << 16);
}
__device__ __forceinline__ float bf_lo(unsigned u){ return __uint_as_float(u << 16); }
__device__ __forceinline__ float bf_hi(unsigned u){ return __uint_as_float(u & 0xFFFF0000u); }

// Hypothesis (B): d_out = 33,554,432 float32 = Re(out[b,j]) at flat b*4096 + j.
// y1 intermediate: packed bf16 complex u32 (re|im<<16) at u32 slot b*4096 + (r*64+l),
// filling the whole buffer; stage 2 rewrites each slab in place with f32 reals.

// ---------------------------------------------------------------------------
// Stage 1:  y1[b, r*64+l] = sum_p w1[r,l,p] * x[b, p*64 + r]
// Block = 4 batches, x rows staged fp32 in LDS.
// ---------------------------------------------------------------------------
__global__ __launch_bounds__(256) void k_n1(const float* __restrict__ x,
                                            const float* __restrict__ w1,
                                            unsigned int* __restrict__ y1){
    __shared__ float XR[16384];
    const int t = threadIdx.x;
    const int b0 = blockIdx.x * 4;

    for (int q = 0; q < 16; ++q) {
        const int fj = (q * 256 + t) * 4;
        *(f32x4*)&XR[fj] = *(const f32x4*)(x + (size_t)b0 * 4096 + fj);
    }
    __syncthreads();

    for (int it = 0; it < 16; ++it) {
        const int idx = it * 256 + t;          // idx = r*64 + l
        const int r = idx >> 6;
        float aR[4] = {0.f,0.f,0.f,0.f}, aI[4] = {0.f,0.f,0.f,0.f};
        const float* wp = w1 + (size_t)idx * 128;    // w1[r][l][*][c]
        for (int pc = 0; pc < 16; ++pc) {            // 4 p per chunk
            f32x4 wa = *(const f32x4*)(wp + pc * 8);     // re,im p=4pc,4pc+1
            f32x4 wb = *(const f32x4*)(wp + pc * 8 + 4); // re,im p=4pc+2,4pc+3
            #pragma unroll
            for (int bq = 0; bq < 4; ++bq) {
                const float x0 = XR[bq * 4096 + (pc * 4 + 0) * 64 + r];
                const float x1 = XR[bq * 4096 + (pc * 4 + 1) * 64 + r];
                const float x2 = XR[bq * 4096 + (pc * 4 + 2) * 64 + r];
                const float x3 = XR[bq * 4096 + (pc * 4 + 3) * 64 + r];
                aR[bq] = fmaf(wa[0], x0, aR[bq]);  aI[bq] = fmaf(wa[1], x0, aI[bq]);
                aR[bq] = fmaf(wa[2], x1, aR[bq]);  aI[bq] = fmaf(wa[3], x1, aI[bq]);
                aR[bq] = fmaf(wb[0], x2, aR[bq]);  aI[bq] = fmaf(wb[1], x2, aI[bq]);
                aR[bq] = fmaf(wb[2], x3, aR[bq]);  aI[bq] = fmaf(wb[3], x3, aI[bq]);
            }
        }
        #pragma unroll
        for (int bq = 0; bq < 4; ++bq)
            y1[(size_t)(b0 + bq) * 4096 + idx] = pack2(aR[bq], aI[bq]);
    }
}

// ---------------------------------------------------------------------------
// Stage 2 (in place, block-local):
//   out_re[b, s*64+l] = sum_r Re( w2[l,s,r] * y1[b, r*64+l] )
//                     = sum_r ( w2re*y1re - w2im*y1im )
// Output: f32 at d_out[b*4096 + s*64 + l].
// ---------------------------------------------------------------------------
__global__ __launch_bounds__(256) void k_n2(const unsigned int* __restrict__ y1,
                                            const float* __restrict__ w2,
                                            float* __restrict__ outf){
    __shared__ unsigned int YS[16384];             // 64 KB: 4 batches x 4096 u32
    const int t = threadIdx.x;
    const int b0 = blockIdx.x * 4;

    for (int q = 0; q < 16; ++q) {
        const int w4 = (q * 256 + t) * 4;          // < 16384
        *(u32x4*)&YS[w4] = *(const u32x4*)(y1 + (size_t)b0 * 4096 + w4);
    }
    __syncthreads();

    for (int it = 0; it < 16; ++it) {
        const int idx = it * 256 + t;              // idx = s*64 + l
        const int s = idx >> 6, l = idx & 63;
        float aR[4] = {0.f,0.f,0.f,0.f};
        const float* wp = w2 + ((size_t)l * 64 + s) * 128;   // w2[l][s][*][c]
        for (int rc = 0; rc < 32; ++rc) {          // 2 r per chunk
            f32x4 wa = *(const f32x4*)(wp + rc * 4);  // re,im r=2rc,2rc+1
            #pragma unroll
            for (int bq = 0; bq < 4; ++bq) {
                const unsigned ya = YS[bq * 4096 + (rc * 2 + 0) * 64 + l];
                const unsigned yb = YS[bq * 4096 + (rc * 2 + 1) * 64 + l];
                aR[bq] = fmaf(wa[0], bf_lo(ya), aR[bq]);
                aR[bq] = fmaf(-wa[1], bf_hi(ya), aR[bq]);
                aR[bq] = fmaf(wa[2], bf_lo(yb), aR[bq]);
                aR[bq] = fmaf(-wa[3], bf_hi(yb), aR[bq]);
            }
        }
        #pragma unroll
        for (int bq = 0; bq < 4; ++bq)
            outf[(size_t)(b0 + bq) * 4096 + idx] = aR[bq];
    }
}

extern "C" void kernel_launch(void* const* d_in, const int* in_sizes, int n_in,
                              void* d_out, int out_size, void* d_ws, size_t ws_size,
                              hipStream_t stream) {
    const float* x  = (const float*)d_in[0];
    const float* w1 = (const float*)d_in[1];
    const float* w2 = (const float*)d_in[2];
    unsigned int* y1 = (unsigned int*)d_out;   // u32 view of the 134 MB output buffer
    float* outf = (float*)d_out;

    k_n1<<<dim3(2048), dim3(256), 0, stream>>>(x, w1, y1);
    k_n2<<<dim3(2048), dim3(256), 0, stream>>>(y1, w2, outf);
}

// Round 9
// 323.820 us; speedup vs baseline: 2.9930x; 2.9930x over previous
//
#include <hip/hip_runtime.h>

typedef __attribute__((ext_vector_type(8))) short short8;
typedef __attribute__((ext_vector_type(4))) float f32x4;
typedef __attribute__((ext_vector_type(4))) unsigned int u32x4;

#define MFMA(a,b,c) __builtin_amdgcn_mfma_f32_16x16x32_bf16((a),(b),(c),0,0,0)

__device__ __forceinline__ unsigned short f2bf(float f){
    unsigned u = __float_as_uint(f);
    u += 0x7FFFu + ((u >> 16) & 1u);   // RNE
    return (unsigned short)(u >> 16);
}
__device__ __forceinline__ unsigned pack2(float lo, float hi){
    return (unsigned)f2bf(lo) | ((unsigned)f2bf(hi) << 16);
}

// d_out: 33,554,432 f32 = Re(out[b,j]) at flat b*4096 + j.
// y1 intermediate: packed bf16 complex u32 (re|im<<16) at u32 slot b*4096 + r*64 + l,
// parked in d_out; stage 2 rewrites each slab in place with f32 reals.

// ---------------------------------------------------------------------------
// Stage 1 (MFMA): y1[b, r*64+l] = sum_p w1[r,l,p] * x[b, p*64+r]
// Block = (16 batches, 16 r). 4 waves = 4 l-quadrants. Verified bit-exact
// vs naive in rounds 2-4.
// ---------------------------------------------------------------------------
__global__ __launch_bounds__(256) void k_stage1(const float* __restrict__ x,
                                                const float* __restrict__ w1,
                                                unsigned int* __restrict__ y1){
    __shared__ unsigned int BF[8192];              // 32 KB
    const int tid = threadIdx.x;
    const int bt = blockIdx.x >> 2, rc = blockIdx.x & 3;
    const int b0 = bt * 16, r0 = rc * 16;

    {   // ---- stage x tile -> LDS (u32-packed bf16 pairs, swizzled) ----
        const int pe = tid >> 3;                   // 0..31 (p-pair)
        const int rq = (tid >> 1) & 3;             // 0..3
        const int bh = tid & 1;                    // 0..1
        const int kc = pe >> 4, gg = (pe >> 2) & 3, jp = pe & 3;
        const float* src = x + (size_t)(b0 + bh * 8) * 4096 + (pe * 2) * 64 + r0 + rq * 4;
        #pragma unroll
        for (int itr = 0; itr < 8; ++itr) {
            f32x4 v0 = *(const f32x4*)(src + (size_t)itr * 4096);
            f32x4 v1 = *(const f32x4*)(src + (size_t)itr * 4096 + 64);
            const int b = bh * 8 + itr;
            const int ROW = ((b ^ (b >> 3) ^ (gg << 1) ^ kc ^ (rq << 2)) & 15) | (gg << 4);
            const int base = kc * 256 + ROW * 4 + jp;
            #pragma unroll
            for (int m = 0; m < 4; ++m)
                BF[(rq * 4 + m) * 512 + base] = pack2(v0[m], v1[m]);
        }
    }
    __syncthreads();

    const int lane = tid & 63, mw = tid >> 6;
    const int Lrow = lane >> 4, idx = lane & 15;

    #pragma unroll
    for (int rr2 = 0; rr2 < 8; ++rr2) {
        const int rA = rr2 * 2;
        f32x4 acc[2][2] = {};                      // [rpair][c]
        #pragma unroll
        for (int kc = 0; kc < 2; ++kc) {
            const int ROWr = ((idx ^ (idx >> 3) ^ (Lrow << 1) ^ kc ^ ((rr2 >> 1) << 2)) & 15) | (Lrow << 4);
            short8 bA = *(const short8*)&BF[(rA + 0) * 512 + kc * 256 + ROWr * 4];
            short8 bB = *(const short8*)&BF[(rA + 1) * 512 + kc * 256 + ROWr * 4];
            #pragma unroll
            for (int rp = 0; rp < 2; ++rp) {
                const int r = r0 + rA + rp;
                const float* wp = w1 + (((size_t)r * 64 + mw * 16 + idx) * 64 + kc * 32 + Lrow * 8) * 2;
                f32x4 q0 = *(const f32x4*)(wp);
                f32x4 q1 = *(const f32x4*)(wp + 4);
                f32x4 q2 = *(const f32x4*)(wp + 8);
                f32x4 q3 = *(const f32x4*)(wp + 12);
                short8 a0, a1;                     // c=0 (re), c=1 (im)
                unsigned* p0 = (unsigned*)&a0; unsigned* p1 = (unsigned*)&a1;
                p0[0] = pack2(q0[0], q0[2]); p0[1] = pack2(q1[0], q1[2]);
                p0[2] = pack2(q2[0], q2[2]); p0[3] = pack2(q3[0], q3[2]);
                p1[0] = pack2(q0[1], q0[3]); p1[1] = pack2(q1[1], q1[3]);
                p1[2] = pack2(q2[1], q2[3]); p1[3] = pack2(q3[1], q3[3]);
                short8 bb = rp ? bB : bA;
                acc[rp][0] = MFMA(a0, bb, acc[rp][0]);
                acc[rp][1] = MFMA(a1, bb, acc[rp][1]);
            }
        }
        #pragma unroll
        for (int rp = 0; rp < 2; ++rp) {
            u32x4 ov;
            #pragma unroll
            for (int reg = 0; reg < 4; ++reg)
                ov[reg] = pack2(acc[rp][0][reg], acc[rp][1][reg]);   // re | im<<16
            // l = mw*16 + Lrow*4 + reg, batch = idx
            *(u32x4*)(y1 + (size_t)(b0 + idx) * 4096 + (size_t)(r0 + rA + rp) * 64 + mw * 16 + Lrow * 4) = ov;
        }
    }
}

// ---------------------------------------------------------------------------
// Stage 2 (MFMA, real output only, in place over d_out):
//   out_re[b, s*64+l] = sum_r ( w2re*y1re - w2im*y1im )[l,s,r]
// Real K'=128 GEMM: B' = interleaved (re,im) over r, A' = (re, -im) pairs.
// Block = (16 batches, 16 l). Reads own slab before barrier, writes same slab.
// ---------------------------------------------------------------------------
__global__ __launch_bounds__(256) void k_stage2(const unsigned int* __restrict__ y1,
                                                const float* __restrict__ w2,
                                                float* __restrict__ outf){
    // Y[li][b][r'] u32, r' = r ^ (b<<2) ^ (((li>>2)&1)<<4)    (64 KB)
    __shared__ unsigned int Y[16384];
    const int tid = threadIdx.x;
    const int bt = blockIdx.x >> 2, lc = blockIdx.x & 3;
    const int b0 = bt * 16, l0 = lc * 16;
    const int lane = tid & 63, mw = tid >> 6;
    const int Lrow = lane >> 4, idx = lane & 15;

    {   // ---- stage y1 l-slice -> LDS (all global reads precede the barrier) ----
        const int r_lo = lane >> 2, cg = lane & 3;
        const int r = mw * 16 + r_lo;
        const unsigned int* src = y1 + (size_t)b0 * 4096 + r * 64 + l0 + cg * 4;
        #pragma unroll
        for (int b = 0; b < 16; ++b) {
            u32x4 v = *(const u32x4*)(src + (size_t)b * 4096);
            const int rsw = r ^ (b << 2) ^ ((cg & 1) << 4);
            #pragma unroll
            for (int q = 0; q < 4; ++q)
                Y[(cg * 4 + q) * 1024 + b * 64 + rsw] = v[q];
        }
    }
    __syncthreads();

    float vRe[4][16];                              // [reg][li]
    #pragma unroll
    for (int li = 0; li < 16; ++li) {
        const int l = l0 + li;
        const float* wp0 = w2 + ((size_t)l * 64 + mw * 16 + idx) * 128;
        const int g1 = ((li >> 2) & 1) << 4;
        f32x4 aRe = {};
        #pragma unroll
        for (int kc = 0; kc < 4; ++kc) {
            const int rb = kc * 16 + Lrow * 4;
            const int rsw = rb ^ (idx << 2) ^ g1;
            short8 bfrag = *(const short8*)&Y[li * 1024 + idx * 64 + rsw];
            const float* wp = wp0 + rb * 2;
            f32x4 u  = *(const f32x4*)wp;          // re0 im0 re1 im1
            f32x4 vv = *(const f32x4*)(wp + 4);    // re2 im2 re3 im3
            short8 are;
            unsigned* pr = (unsigned*)&are;
            pr[0] = pack2(u[0], -u[1]);   pr[1] = pack2(u[2], -u[3]);
            pr[2] = pack2(vv[0], -vv[1]); pr[3] = pack2(vv[2], -vv[3]);
            aRe = MFMA(are, bfrag, aRe);
        }
        #pragma unroll
        for (int reg = 0; reg < 4; ++reg)
            vRe[reg][li] = aRe[reg];
    }

    // ---- store: per (reg) a 64-B contiguous f32 run of 16 l's ----
    #pragma unroll
    for (int reg = 0; reg < 4; ++reg) {
        float* dst = outf + (size_t)(b0 + idx) * 4096 + (size_t)(mw * 16 + Lrow * 4 + reg) * 64 + l0;
        #pragma unroll
        for (int h = 0; h < 4; ++h) {
            f32x4 wv = { vRe[0][0], 0, 0, 0 };     // placeholder, overwritten below
            wv[0] = vRe[reg][h*4+0]; wv[1] = vRe[reg][h*4+1];
            wv[2] = vRe[reg][h*4+2]; wv[3] = vRe[reg][h*4+3];
            *(f32x4*)(dst + h * 4) = wv;
        }
    }
}

extern "C" void kernel_launch(void* const* d_in, const int* in_sizes, int n_in,
                              void* d_out, int out_size, void* d_ws, size_t ws_size,
                              hipStream_t stream) {
    const float* x  = (const float*)d_in[0];
    const float* w1 = (const float*)d_in[1];
    const float* w2 = (const float*)d_in[2];
    unsigned int* y1 = (unsigned int*)d_out;   // u32 view of the 134 MB output buffer
    float* outf = (float*)d_out;

    k_stage1<<<dim3(2048), dim3(256), 0, stream>>>(x, w1, y1);
    k_stage2<<<dim3(2048), dim3(256), 0, stream>>>(y1, w2, outf);
}

// Round 10
// 179.697 us; speedup vs baseline: 5.3935x; 1.8020x over previous
//
#include <hip/hip_runtime.h>

typedef __attribute__((ext_vector_type(8))) short short8;
typedef __attribute__((ext_vector_type(4))) float f32x4;
typedef __attribute__((ext_vector_type(4))) unsigned int u32x4;

#define MFMA(a,b,c) __builtin_amdgcn_mfma_f32_16x16x32_bf16((a),(b),(c),0,0,0)

__device__ __forceinline__ unsigned short f2bf(float f){
    unsigned u = __float_as_uint(f);
    u += 0x7FFFu + ((u >> 16) & 1u);   // RNE
    return (unsigned short)(u >> 16);
}
__device__ __forceinline__ unsigned pack2(float lo, float hi){
    return (unsigned)f2bf(lo) | ((unsigned)f2bf(hi) << 16);
}

// d_out: 33,554,432 f32 = Re(out[b,j]) at flat b*4096 + j.
// y1 intermediate: packed bf16 complex u32 (re|im<<16) at u32 slot b*4096 + r*64 + l,
// parked in d_out; stage 2 rewrites each slab in place with f32 reals.
//
// d_ws (fast path, needs 2 MiB): fragment-ready bf16 weights.
//  w1f fragment-row g = (((r*2 + c)*2 + kc)*4 + mw)*64 + lane  (65536 rows x 8 bf16)
//      element j = w1[r][mw*16+(lane&15)][kc*32+(lane>>4)*8+j].c
//  w2f fragment-row h = ((l*4 + kc)*4 + mw)*64 + lane          (65536 rows x 8 bf16)
//      element j = (j&1 ? -im : re) w2[l][mw*16+(lane&15)][kc*16+(lane>>4)*4+(j>>1)]

// ---------------------------------------------------------------------------
__global__ __launch_bounds__(256) void k_prep(const float* __restrict__ w1,
                                              const float* __restrict__ w2,
                                              unsigned int* __restrict__ w1f,
                                              unsigned int* __restrict__ w2f){
    const int g = blockIdx.x * 256 + threadIdx.x;
    if (g < 65536) {
        const int lane = g & 63, mw = (g >> 6) & 3, kc = (g >> 8) & 1, c = (g >> 9) & 1, r = g >> 10;
        const int Lrow = lane >> 4, idx = lane & 15;
        const float* src = w1 + ((size_t)(r * 64 + mw * 16 + idx) * 64 + kc * 32 + Lrow * 8) * 2 + c;
        unsigned o[4];
        #pragma unroll
        for (int jp = 0; jp < 4; ++jp)
            o[jp] = pack2(src[jp * 4], src[jp * 4 + 2]);
        *(u32x4*)(w1f + (size_t)g * 4) = *(u32x4*)o;
    } else {
        const int h = g - 65536;
        const int lane = h & 63, mw = (h >> 6) & 3, kc = (h >> 8) & 3, l = h >> 10;
        const int Lrow = lane >> 4, idx = lane & 15;
        const float* src = w2 + ((size_t)(l * 64 + mw * 16 + idx) * 64 + kc * 16 + Lrow * 4) * 2;
        unsigned o[4];
        #pragma unroll
        for (int jp = 0; jp < 4; ++jp)
            o[jp] = pack2(src[jp * 2], -src[jp * 2 + 1]);   // (re, -im)
        *(u32x4*)(w2f + (size_t)h * 4) = *(u32x4*)o;
    }
}

// ---------------------------------------------------------------------------
// Stage 1 (fast): y1[b, r*64+l] = sum_p w1[r,l,p] * x[b, p*64+r]
// ---------------------------------------------------------------------------
__global__ __launch_bounds__(256) void k_stage1f(const float* __restrict__ x,
                                                 const unsigned short* __restrict__ w1b,
                                                 unsigned int* __restrict__ y1){
    __shared__ unsigned int BF[8192];              // 32 KB
    const int tid = threadIdx.x;
    const int bt = blockIdx.x >> 2, rc = blockIdx.x & 3;
    const int b0 = bt * 16, r0 = rc * 16;

    {   // ---- stage x tile -> LDS (u32-packed bf16 pairs, swizzled) ----
        const int pe = tid >> 3;
        const int rq = (tid >> 1) & 3;
        const int bh = tid & 1;
        const int kc = pe >> 4, gg = (pe >> 2) & 3, jp = pe & 3;
        const float* src = x + (size_t)(b0 + bh * 8) * 4096 + (pe * 2) * 64 + r0 + rq * 4;
        #pragma unroll
        for (int itr = 0; itr < 8; ++itr) {
            f32x4 v0 = *(const f32x4*)(src + (size_t)itr * 4096);
            f32x4 v1 = *(const f32x4*)(src + (size_t)itr * 4096 + 64);
            const int b = bh * 8 + itr;
            const int ROW = ((b ^ (b >> 3) ^ (gg << 1) ^ kc ^ (rq << 2)) & 15) | (gg << 4);
            const int base = kc * 256 + ROW * 4 + jp;
            #pragma unroll
            for (int m = 0; m < 4; ++m)
                BF[(rq * 4 + m) * 512 + base] = pack2(v0[m], v1[m]);
        }
    }
    __syncthreads();

    const int lane = tid & 63, mw = tid >> 6;
    const int Lrow = lane >> 4, idx = lane & 15;
    const unsigned short* wbase = w1b + mw * 512 + lane * 8;

    #pragma unroll
    for (int rr2 = 0; rr2 < 8; ++rr2) {
        const int rA = rr2 * 2;
        f32x4 acc[2][2] = {};
        #pragma unroll
        for (int kc = 0; kc < 2; ++kc) {
            const int ROWr = ((idx ^ (idx >> 3) ^ (Lrow << 1) ^ kc ^ ((rr2 >> 1) << 2)) & 15) | (Lrow << 4);
            short8 bA = *(const short8*)&BF[(rA + 0) * 512 + kc * 256 + ROWr * 4];
            short8 bB = *(const short8*)&BF[(rA + 1) * 512 + kc * 256 + ROWr * 4];
            #pragma unroll
            for (int rp = 0; rp < 2; ++rp) {
                const size_t wb = (size_t)(r0 + rA + rp) * 8192 + kc * 2048;
                short8 a0 = *(const short8*)(wbase + wb);          // re
                short8 a1 = *(const short8*)(wbase + wb + 4096);   // im
                short8 bb = rp ? bB : bA;
                acc[rp][0] = MFMA(a0, bb, acc[rp][0]);
                acc[rp][1] = MFMA(a1, bb, acc[rp][1]);
            }
        }
        #pragma unroll
        for (int rp = 0; rp < 2; ++rp) {
            u32x4 ov;
            #pragma unroll
            for (int reg = 0; reg < 4; ++reg)
                ov[reg] = pack2(acc[rp][0][reg], acc[rp][1][reg]);   // re | im<<16
            *(u32x4*)(y1 + (size_t)(b0 + idx) * 4096 + (size_t)(r0 + rA + rp) * 64 + mw * 16 + Lrow * 4) = ov;
        }
    }
}

// ---------------------------------------------------------------------------
// Stage 2 (fast, real output only, in place over d_out):
//   out_re[b, s*64+l] = sum_r ( w2re*y1re - w2im*y1im )[l,s,r]
// ---------------------------------------------------------------------------
__global__ __launch_bounds__(256) void k_stage2f(const unsigned int* __restrict__ y1,
                                                 const unsigned short* __restrict__ w2b,
                                                 float* __restrict__ outf){
    __shared__ unsigned int Y[16384];              // 64 KB
    const int tid = threadIdx.x;
    const int bt = blockIdx.x >> 2, lc = blockIdx.x & 3;
    const int b0 = bt * 16, l0 = lc * 16;
    const int lane = tid & 63, mw = tid >> 6;
    const int Lrow = lane >> 4, idx = lane & 15;

    {   // ---- stage y1 l-slice -> LDS (all global reads precede the barrier) ----
        const int r_lo = lane >> 2, cg = lane & 3;
        const int r = mw * 16 + r_lo;
        const unsigned int* src = y1 + (size_t)b0 * 4096 + r * 64 + l0 + cg * 4;
        #pragma unroll
        for (int b = 0; b < 16; ++b) {
            u32x4 v = *(const u32x4*)(src + (size_t)b * 4096);
            const int rsw = r ^ (b << 2) ^ ((cg & 1) << 4);
            #pragma unroll
            for (int q = 0; q < 4; ++q)
                Y[(cg * 4 + q) * 1024 + b * 64 + rsw] = v[q];
        }
    }
    __syncthreads();

    const unsigned short* wbase = w2b + mw * 512 + lane * 8;
    float vRe[4][16];
    #pragma unroll
    for (int li = 0; li < 16; ++li) {
        const int l = l0 + li;
        const int g1 = ((li >> 2) & 1) << 4;
        f32x4 aRe = {};
        #pragma unroll
        for (int kc = 0; kc < 4; ++kc) {
            const int rb = kc * 16 + Lrow * 4;
            const int rsw = rb ^ (idx << 2) ^ g1;
            short8 bfrag = *(const short8*)&Y[li * 1024 + idx * 64 + rsw];
            short8 are   = *(const short8*)(wbase + (size_t)l * 8192 + kc * 2048);
            aRe = MFMA(are, bfrag, aRe);
        }
        #pragma unroll
        for (int reg = 0; reg < 4; ++reg)
            vRe[reg][li] = aRe[reg];
    }

    #pragma unroll
    for (int reg = 0; reg < 4; ++reg) {
        float* dst = outf + (size_t)(b0 + idx) * 4096 + (size_t)(mw * 16 + Lrow * 4 + reg) * 64 + l0;
        #pragma unroll
        for (int h = 0; h < 4; ++h) {
            f32x4 wv;
            wv[0] = vRe[reg][h*4+0]; wv[1] = vRe[reg][h*4+1];
            wv[2] = vRe[reg][h*4+2]; wv[3] = vRe[reg][h*4+3];
            *(f32x4*)(dst + h * 4) = wv;
        }
    }
}

// ===========================================================================
// Fallback path (round-9 verified kernels) — used only if ws_size < 2 MiB.
// ===========================================================================
__global__ __launch_bounds__(256) void k_stage1(const float* __restrict__ x,
                                                const float* __restrict__ w1,
                                                unsigned int* __restrict__ y1){
    __shared__ unsigned int BF[8192];
    const int tid = threadIdx.x;
    const int bt = blockIdx.x >> 2, rc = blockIdx.x & 3;
    const int b0 = bt * 16, r0 = rc * 16;
    {
        const int pe = tid >> 3;
        const int rq = (tid >> 1) & 3;
        const int bh = tid & 1;
        const int kc = pe >> 4, gg = (pe >> 2) & 3, jp = pe & 3;
        const float* src = x + (size_t)(b0 + bh * 8) * 4096 + (pe * 2) * 64 + r0 + rq * 4;
        #pragma unroll
        for (int itr = 0; itr < 8; ++itr) {
            f32x4 v0 = *(const f32x4*)(src + (size_t)itr * 4096);
            f32x4 v1 = *(const f32x4*)(src + (size_t)itr * 4096 + 64);
            const int b = bh * 8 + itr;
            const int ROW = ((b ^ (b >> 3) ^ (gg << 1) ^ kc ^ (rq << 2)) & 15) | (gg << 4);
            const int base = kc * 256 + ROW * 4 + jp;
            #pragma unroll
            for (int m = 0; m < 4; ++m)
                BF[(rq * 4 + m) * 512 + base] = pack2(v0[m], v1[m]);
        }
    }
    __syncthreads();
    const int lane = tid & 63, mw = tid >> 6;
    const int Lrow = lane >> 4, idx = lane & 15;
    #pragma unroll
    for (int rr2 = 0; rr2 < 8; ++rr2) {
        const int rA = rr2 * 2;
        f32x4 acc[2][2] = {};
        #pragma unroll
        for (int kc = 0; kc < 2; ++kc) {
            const int ROWr = ((idx ^ (idx >> 3) ^ (Lrow << 1) ^ kc ^ ((rr2 >> 1) << 2)) & 15) | (Lrow << 4);
            short8 bA = *(const short8*)&BF[(rA + 0) * 512 + kc * 256 + ROWr * 4];
            short8 bB = *(const short8*)&BF[(rA + 1) * 512 + kc * 256 + ROWr * 4];
            #pragma unroll
            for (int rp = 0; rp < 2; ++rp) {
                const int r = r0 + rA + rp;
                const float* wp = w1 + (((size_t)r * 64 + mw * 16 + idx) * 64 + kc * 32 + Lrow * 8) * 2;
                f32x4 q0 = *(const f32x4*)(wp);
                f32x4 q1 = *(const f32x4*)(wp + 4);
                f32x4 q2 = *(const f32x4*)(wp + 8);
                f32x4 q3 = *(const f32x4*)(wp + 12);
                short8 a0, a1;
                unsigned* p0 = (unsigned*)&a0; unsigned* p1 = (unsigned*)&a1;
                p0[0] = pack2(q0[0], q0[2]); p0[1] = pack2(q1[0], q1[2]);
                p0[2] = pack2(q2[0], q2[2]); p0[3] = pack2(q3[0], q3[2]);
                p1[0] = pack2(q0[1], q0[3]); p1[1] = pack2(q1[1], q1[3]);
                p1[2] = pack2(q2[1], q2[3]); p1[3] = pack2(q3[1], q3[3]);
                short8 bb = rp ? bB : bA;
                acc[rp][0] = MFMA(a0, bb, acc[rp][0]);
                acc[rp][1] = MFMA(a1, bb, acc[rp][1]);
            }
        }
        #pragma unroll
        for (int rp = 0; rp < 2; ++rp) {
            u32x4 ov;
            #pragma unroll
            for (int reg = 0; reg < 4; ++reg)
                ov[reg] = pack2(acc[rp][0][reg], acc[rp][1][reg]);
            *(u32x4*)(y1 + (size_t)(b0 + idx) * 4096 + (size_t)(r0 + rA + rp) * 64 + mw * 16 + Lrow * 4) = ov;
        }
    }
}

__global__ __launch_bounds__(256) void k_stage2(const unsigned int* __restrict__ y1,
                                                const float* __restrict__ w2,
                                                float* __restrict__ outf){
    __shared__ unsigned int Y[16384];
    const int tid = threadIdx.x;
    const int bt = blockIdx.x >> 2, lc = blockIdx.x & 3;
    const int b0 = bt * 16, l0 = lc * 16;
    const int lane = tid & 63, mw = tid >> 6;
    const int Lrow = lane >> 4, idx = lane & 15;
    {
        const int r_lo = lane >> 2, cg = lane & 3;
        const int r = mw * 16 + r_lo;
        const unsigned int* src = y1 + (size_t)b0 * 4096 + r * 64 + l0 + cg * 4;
        #pragma unroll
        for (int b = 0; b < 16; ++b) {
            u32x4 v = *(const u32x4*)(src + (size_t)b * 4096);
            const int rsw = r ^ (b << 2) ^ ((cg & 1) << 4);
            #pragma unroll
            for (int q = 0; q < 4; ++q)
                Y[(cg * 4 + q) * 1024 + b * 64 + rsw] = v[q];
        }
    }
    __syncthreads();
    float vRe[4][16];
    #pragma unroll
    for (int li = 0; li < 16; ++li) {
        const int l = l0 + li;
        const float* wp0 = w2 + ((size_t)l * 64 + mw * 16 + idx) * 128;
        const int g1 = ((li >> 2) & 1) << 4;
        f32x4 aRe = {};
        #pragma unroll
        for (int kc = 0; kc < 4; ++kc) {
            const int rb = kc * 16 + Lrow * 4;
            const int rsw = rb ^ (idx << 2) ^ g1;
            short8 bfrag = *(const short8*)&Y[li * 1024 + idx * 64 + rsw];
            const float* wp = wp0 + rb * 2;
            f32x4 u  = *(const f32x4*)wp;
            f32x4 vv = *(const f32x4*)(wp + 4);
            short8 are;
            unsigned* pr = (unsigned*)&are;
            pr[0] = pack2(u[0], -u[1]);   pr[1] = pack2(u[2], -u[3]);
            pr[2] = pack2(vv[0], -vv[1]); pr[3] = pack2(vv[2], -vv[3]);
            aRe = MFMA(are, bfrag, aRe);
        }
        #pragma unroll
        for (int reg = 0; reg < 4; ++reg)
            vRe[reg][li] = aRe[reg];
    }
    #pragma unroll
    for (int reg = 0; reg < 4; ++reg) {
        float* dst = outf + (size_t)(b0 + idx) * 4096 + (size_t)(mw * 16 + Lrow * 4 + reg) * 64 + l0;
        #pragma unroll
        for (int h = 0; h < 4; ++h) {
            f32x4 wv;
            wv[0] = vRe[reg][h*4+0]; wv[1] = vRe[reg][h*4+1];
            wv[2] = vRe[reg][h*4+2]; wv[3] = vRe[reg][h*4+3];
            *(f32x4*)(dst + h * 4) = wv;
        }
    }
}

extern "C" void kernel_launch(void* const* d_in, const int* in_sizes, int n_in,
                              void* d_out, int out_size, void* d_ws, size_t ws_size,
                              hipStream_t stream) {
    const float* x  = (const float*)d_in[0];
    const float* w1 = (const float*)d_in[1];
    const float* w2 = (const float*)d_in[2];
    unsigned int* y1 = (unsigned int*)d_out;
    float* outf = (float*)d_out;

    if (ws_size >= (size_t)2 * 1024 * 1024) {
        unsigned int* w1f = (unsigned int*)d_ws;           // 1 MiB
        unsigned int* w2f = w1f + 262144;                  // 1 MiB
        k_prep   <<<dim3(512),  dim3(256), 0, stream>>>(w1, w2, w1f, w2f);
        k_stage1f<<<dim3(2048), dim3(256), 0, stream>>>(x, (const unsigned short*)w1f, y1);
        k_stage2f<<<dim3(2048), dim3(256), 0, stream>>>(y1, (const unsigned short*)w2f, outf);
    } else {
        k_stage1<<<dim3(2048), dim3(256), 0, stream>>>(x, w1, y1);
        k_stage2<<<dim3(2048), dim3(256), 0, stream>>>(y1, w2, outf);
    }
}

// Round 11
// 133.333 us; speedup vs baseline: 7.2689x; 1.3477x over previous
//
#include <hip/hip_runtime.h>

typedef __attribute__((ext_vector_type(8))) short short8;
typedef __attribute__((ext_vector_type(4))) float f32x4;
typedef __attribute__((ext_vector_type(4))) unsigned int u32x4;

#define MFMA(a,b,c) __builtin_amdgcn_mfma_f32_16x16x32_bf16((a),(b),(c),0,0,0)

__device__ __forceinline__ unsigned short f2bf(float f){
    unsigned u = __float_as_uint(f);
    u += 0x7FFFu + ((u >> 16) & 1u);   // RNE
    return (unsigned short)(u >> 16);
}
__device__ __forceinline__ unsigned pack2(float lo, float hi){
    return (unsigned)f2bf(lo) | ((unsigned)f2bf(hi) << 16);
}

// d_out: 33,554,432 f32 = Re(out[b,j]) at flat b*4096 + j.
// y1 intermediate: packed bf16 complex u32 (re|im<<16) at u32 slot b*4096 + r*64 + l.
// d_ws (>=2 MiB): fragment-ready bf16 weights (same layouts as round 10).

// ---------------------------------------------------------------------------
__global__ __launch_bounds__(256) void k_prep(const float* __restrict__ w1,
                                              const float* __restrict__ w2,
                                              unsigned int* __restrict__ w1f,
                                              unsigned int* __restrict__ w2f){
    const int g = blockIdx.x * 256 + threadIdx.x;
    if (g < 65536) {
        const int lane = g & 63, mw = (g >> 6) & 3, kc = (g >> 8) & 1, c = (g >> 9) & 1, r = g >> 10;
        const int Lrow = lane >> 4, idx = lane & 15;
        const float* src = w1 + ((size_t)(r * 64 + mw * 16 + idx) * 64 + kc * 32 + Lrow * 8) * 2 + c;
        unsigned o[4];
        #pragma unroll
        for (int jp = 0; jp < 4; ++jp)
            o[jp] = pack2(src[jp * 4], src[jp * 4 + 2]);
        *(u32x4*)(w1f + (size_t)g * 4) = *(u32x4*)o;
    } else {
        const int h = g - 65536;
        const int lane = h & 63, mw = (h >> 6) & 3, kc = (h >> 8) & 3, l = h >> 10;
        const int Lrow = lane >> 4, idx = lane & 15;
        const float* src = w2 + ((size_t)(l * 64 + mw * 16 + idx) * 64 + kc * 16 + Lrow * 4) * 2;
        unsigned o[4];
        #pragma unroll
        for (int jp = 0; jp < 4; ++jp)
            o[jp] = pack2(src[jp * 2], -src[jp * 2 + 1]);   // (re, -im)
        *(u32x4*)(w2f + (size_t)h * 4) = *(u32x4*)o;
    }
}

// ---------------------------------------------------------------------------
// Stage 1 (fast): y1[b, r*64+l] = sum_p w1[r,l,p] * x[b, p*64+r]
// New: results collected in regs, transposed through LDS (after BF is dead),
// stored as 256-B contiguous (b, r)-rows. XCD pair-swizzle on (bt, rc).
// ---------------------------------------------------------------------------
__global__ __launch_bounds__(256) void k_stage1f(const float* __restrict__ x,
                                                 const unsigned short* __restrict__ w1b,
                                                 unsigned int* __restrict__ y1){
    __shared__ unsigned int BF[8192];              // 32 KB
    const int tid = threadIdx.x;
    const int bid = blockIdx.x;
    // pair swizzle: (bt, rc=2k) at bid B, (bt, rc=2k+1) at B+8 (same XCD, adjacent)
    const int inner = (bid >> 3) & 1;
    const int pp = (bid >> 4) * 8 + (bid & 7);
    const int bt = pp >> 1, rc = (pp & 1) * 2 + inner;
    const int b0 = bt * 16, r0 = rc * 16;

    {   // ---- stage x tile -> LDS (u32-packed bf16 pairs, swizzled) ----
        const int pe = tid >> 3;
        const int rq = (tid >> 1) & 3;
        const int bh = tid & 1;
        const int kc = pe >> 4, gg = (pe >> 2) & 3, jp = pe & 3;
        const float* src = x + (size_t)(b0 + bh * 8) * 4096 + (pe * 2) * 64 + r0 + rq * 4;
        #pragma unroll
        for (int itr = 0; itr < 8; ++itr) {
            f32x4 v0 = *(const f32x4*)(src + (size_t)itr * 4096);
            f32x4 v1 = *(const f32x4*)(src + (size_t)itr * 4096 + 64);
            const int b = bh * 8 + itr;
            const int ROW = ((b ^ (b >> 3) ^ (gg << 1) ^ kc ^ (rq << 2)) & 15) | (gg << 4);
            const int base = kc * 256 + ROW * 4 + jp;
            #pragma unroll
            for (int m = 0; m < 4; ++m)
                BF[(rq * 4 + m) * 512 + base] = pack2(v0[m], v1[m]);
        }
    }
    __syncthreads();

    const int lane = tid & 63, mw = tid >> 6;
    const int Lrow = lane >> 4, idx = lane & 15;
    const unsigned short* wbase = w1b + mw * 512 + lane * 8;

    u32x4 ou[8][2];                                // all outputs in regs (64 VGPR)

    #pragma unroll
    for (int rr2 = 0; rr2 < 8; ++rr2) {
        const int rA = rr2 * 2;
        f32x4 acc[2][2] = {};
        #pragma unroll
        for (int kc = 0; kc < 2; ++kc) {
            const int ROWr = ((idx ^ (idx >> 3) ^ (Lrow << 1) ^ kc ^ ((rr2 >> 1) << 2)) & 15) | (Lrow << 4);
            short8 bA = *(const short8*)&BF[(rA + 0) * 512 + kc * 256 + ROWr * 4];
            short8 bB = *(const short8*)&BF[(rA + 1) * 512 + kc * 256 + ROWr * 4];
            #pragma unroll
            for (int rp = 0; rp < 2; ++rp) {
                const size_t wb = (size_t)(r0 + rA + rp) * 8192 + kc * 2048;
                short8 a0 = *(const short8*)(wbase + wb);          // re
                short8 a1 = *(const short8*)(wbase + wb + 4096);   // im
                short8 bb = rp ? bB : bA;
                acc[rp][0] = MFMA(a0, bb, acc[rp][0]);
                acc[rp][1] = MFMA(a1, bb, acc[rp][1]);
            }
        }
        #pragma unroll
        for (int rp = 0; rp < 2; ++rp) {
            u32x4 ov;
            #pragma unroll
            for (int reg = 0; reg < 4; ++reg)
                ov[reg] = pack2(acc[rp][0][reg], acc[rp][1][reg]);   // re | im<<16
            ou[rr2][rp] = ov;
        }
    }

    // ---- transpose through BF (dead now), two 32-KB halves ----
    const int l4 = mw * 16 + Lrow * 4;
    #pragma unroll
    for (int h = 0; h < 2; ++h) {
        __syncthreads();
        // write: phys(b, rloc, l) = b*512 + rloc*64 + (l ^ ((b&7)<<2))
        #pragma unroll
        for (int rr2 = h * 4; rr2 < h * 4 + 4; ++rr2) {
            #pragma unroll
            for (int rp = 0; rp < 2; ++rp) {
                const int rloc = rr2 * 2 + rp - h * 8;
                *(u32x4*)&BF[idx * 512 + rloc * 64 + ((l4 ^ ((idx & 7) << 2)))] = ou[rr2][rp];
            }
        }
        __syncthreads();
        // read + coalesced store: per rloc, 256 threads cover 16 b x 16 l-quads
        const int b = tid >> 4, quad = tid & 15;
        #pragma unroll
        for (int rloc = 0; rloc < 8; ++rloc) {
            u32x4 v = *(const u32x4*)&BF[b * 512 + rloc * 64 + (((quad * 4) ^ ((b & 7) << 2)))];
            *(u32x4*)(y1 + (size_t)(b0 + b) * 4096 + (size_t)(r0 + h * 8 + rloc) * 64 + quad * 4) = v;
        }
    }
}

// ---------------------------------------------------------------------------
// Stage 2 (fast, real output only, in place over d_out):
//   out_re[b, s*64+l] = sum_r ( w2re*y1re - w2im*y1im )[l,s,r]
// New: results transposed through Y-LDS (dead after MFMA), stored 64-B
// coalesced. XCD pair-swizzle on (bt, lc) merges 128-B output lines.
// ---------------------------------------------------------------------------
__global__ __launch_bounds__(256) void k_stage2f(const unsigned int* __restrict__ y1,
                                                 const unsigned short* __restrict__ w2b,
                                                 float* __restrict__ outf){
    __shared__ unsigned int Y[16384];              // 64 KB
    const int tid = threadIdx.x;
    const int bid = blockIdx.x;
    const int inner = (bid >> 3) & 1;
    const int pp = (bid >> 4) * 8 + (bid & 7);
    const int bt = pp >> 1, lc = (pp & 1) * 2 + inner;
    const int b0 = bt * 16, l0 = lc * 16;
    const int lane = tid & 63, mw = tid >> 6;
    const int Lrow = lane >> 4, idx = lane & 15;

    {   // ---- stage y1 l-slice -> LDS (all global reads precede the barrier) ----
        const int r_lo = lane >> 2, cg = lane & 3;
        const int r = mw * 16 + r_lo;
        const unsigned int* src = y1 + (size_t)b0 * 4096 + r * 64 + l0 + cg * 4;
        #pragma unroll
        for (int b = 0; b < 16; ++b) {
            u32x4 v = *(const u32x4*)(src + (size_t)b * 4096);
            const int rsw = r ^ (b << 2) ^ ((cg & 1) << 4);
            #pragma unroll
            for (int q = 0; q < 4; ++q)
                Y[(cg * 4 + q) * 1024 + b * 64 + rsw] = v[q];
        }
    }
    __syncthreads();

    const unsigned short* wbase = w2b + mw * 512 + lane * 8;
    float vRe[4][16];
    #pragma unroll
    for (int li = 0; li < 16; ++li) {
        const int l = l0 + li;
        const int g1 = ((li >> 2) & 1) << 4;
        f32x4 aRe = {};
        #pragma unroll
        for (int kc = 0; kc < 4; ++kc) {
            const int rb = kc * 16 + Lrow * 4;
            const int rsw = rb ^ (idx << 2) ^ g1;
            short8 bfrag = *(const short8*)&Y[li * 1024 + idx * 64 + rsw];
            short8 are   = *(const short8*)(wbase + (size_t)l * 8192 + kc * 2048);
            aRe = MFMA(are, bfrag, aRe);
        }
        #pragma unroll
        for (int reg = 0; reg < 4; ++reg)
            vRe[reg][li] = aRe[reg];
    }

    // ---- transpose through Y (dead now): phys(b,s,li) = b*1024 + s*16 + (li ^ ((b&3)<<2)) ----
    __syncthreads();
    float* Yf = (float*)Y;
    #pragma unroll
    for (int reg = 0; reg < 4; ++reg) {
        const int s = mw * 16 + Lrow * 4 + reg;
        #pragma unroll
        for (int q = 0; q < 4; ++q) {
            f32x4 v = { vRe[reg][q*4+0], vRe[reg][q*4+1], vRe[reg][q*4+2], vRe[reg][q*4+3] };
            *(f32x4*)&Yf[idx * 1024 + s * 16 + (((q ^ (idx & 3)) << 2))] = v;
        }
    }
    __syncthreads();

    {   // ---- coalesced store: per b, lanes cover (s, c4): 64-B quads ----
        const int s2 = tid >> 2, c4 = tid & 3;
        #pragma unroll
        for (int i = 0; i < 16; ++i) {
            f32x4 v = *(const f32x4*)&Yf[i * 1024 + s2 * 16 + (((c4 ^ (i & 3)) << 2))];
            *(f32x4*)(outf + (size_t)(b0 + i) * 4096 + s2 * 64 + l0 + c4 * 4) = v;
        }
    }
}

// ===========================================================================
// Fallback path (round-9 verified kernels) — used only if ws_size < 2 MiB.
// ===========================================================================
__global__ __launch_bounds__(256) void k_stage1(const float* __restrict__ x,
                                                const float* __restrict__ w1,
                                                unsigned int* __restrict__ y1){
    __shared__ unsigned int BF[8192];
    const int tid = threadIdx.x;
    const int bt = blockIdx.x >> 2, rc = blockIdx.x & 3;
    const int b0 = bt * 16, r0 = rc * 16;
    {
        const int pe = tid >> 3;
        const int rq = (tid >> 1) & 3;
        const int bh = tid & 1;
        const int kc = pe >> 4, gg = (pe >> 2) & 3, jp = pe & 3;
        const float* src = x + (size_t)(b0 + bh * 8) * 4096 + (pe * 2) * 64 + r0 + rq * 4;
        #pragma unroll
        for (int itr = 0; itr < 8; ++itr) {
            f32x4 v0 = *(const f32x4*)(src + (size_t)itr * 4096);
            f32x4 v1 = *(const f32x4*)(src + (size_t)itr * 4096 + 64);
            const int b = bh * 8 + itr;
            const int ROW = ((b ^ (b >> 3) ^ (gg << 1) ^ kc ^ (rq << 2)) & 15) | (gg << 4);
            const int base = kc * 256 + ROW * 4 + jp;
            #pragma unroll
            for (int m = 0; m < 4; ++m)
                BF[(rq * 4 + m) * 512 + base] = pack2(v0[m], v1[m]);
        }
    }
    __syncthreads();
    const int lane = tid & 63, mw = tid >> 6;
    const int Lrow = lane >> 4, idx = lane & 15;
    #pragma unroll
    for (int rr2 = 0; rr2 < 8; ++rr2) {
        const int rA = rr2 * 2;
        f32x4 acc[2][2] = {};
        #pragma unroll
        for (int kc = 0; kc < 2; ++kc) {
            const int ROWr = ((idx ^ (idx >> 3) ^ (Lrow << 1) ^ kc ^ ((rr2 >> 1) << 2)) & 15) | (Lrow << 4);
            short8 bA = *(const short8*)&BF[(rA + 0) * 512 + kc * 256 + ROWr * 4];
            short8 bB = *(const short8*)&BF[(rA + 1) * 512 + kc * 256 + ROWr * 4];
            #pragma unroll
            for (int rp = 0; rp < 2; ++rp) {
                const int r = r0 + rA + rp;
                const float* wp = w1 + (((size_t)r * 64 + mw * 16 + idx) * 64 + kc * 32 + Lrow * 8) * 2;
                f32x4 q0 = *(const f32x4*)(wp);
                f32x4 q1 = *(const f32x4*)(wp + 4);
                f32x4 q2 = *(const f32x4*)(wp + 8);
                f32x4 q3 = *(const f32x4*)(wp + 12);
                short8 a0, a1;
                unsigned* p0 = (unsigned*)&a0; unsigned* p1 = (unsigned*)&a1;
                p0[0] = pack2(q0[0], q0[2]); p0[1] = pack2(q1[0], q1[2]);
                p0[2] = pack2(q2[0], q2[2]); p0[3] = pack2(q3[0], q3[2]);
                p1[0] = pack2(q0[1], q0[3]); p1[1] = pack2(q1[1], q1[3]);
                p1[2] = pack2(q2[1], q2[3]); p1[3] = pack2(q3[1], q3[3]);
                short8 bb = rp ? bB : bA;
                acc[rp][0] = MFMA(a0, bb, acc[rp][0]);
                acc[rp][1] = MFMA(a1, bb, acc[rp][1]);
            }
        }
        #pragma unroll
        for (int rp = 0; rp < 2; ++rp) {
            u32x4 ov;
            #pragma unroll
            for (int reg = 0; reg < 4; ++reg)
                ov[reg] = pack2(acc[rp][0][reg], acc[rp][1][reg]);
            *(u32x4*)(y1 + (size_t)(b0 + idx) * 4096 + (size_t)(r0 + rA + rp) * 64 + mw * 16 + Lrow * 4) = ov;
        }
    }
}

__global__ __launch_bounds__(256) void k_stage2(const unsigned int* __restrict__ y1,
                                                const float* __restrict__ w2,
                                                float* __restrict__ outf){
    __shared__ unsigned int Y[16384];
    const int tid = threadIdx.x;
    const int bt = blockIdx.x >> 2, lc = blockIdx.x & 3;
    const int b0 = bt * 16, l0 = lc * 16;
    const int lane = tid & 63, mw = tid >> 6;
    const int Lrow = lane >> 4, idx = lane & 15;
    {
        const int r_lo = lane >> 2, cg = lane & 3;
        const int r = mw * 16 + r_lo;
        const unsigned int* src = y1 + (size_t)b0 * 4096 + r * 64 + l0 + cg * 4;
        #pragma unroll
        for (int b = 0; b < 16; ++b) {
            u32x4 v = *(const u32x4*)(src + (size_t)b * 4096);
            const int rsw = r ^ (b << 2) ^ ((cg & 1) << 4);
            #pragma unroll
            for (int q = 0; q < 4; ++q)
                Y[(cg * 4 + q) * 1024 + b * 64 + rsw] = v[q];
        }
    }
    __syncthreads();
    float vRe[4][16];
    #pragma unroll
    for (int li = 0; li < 16; ++li) {
        const int l = l0 + li;
        const float* wp0 = w2 + ((size_t)l * 64 + mw * 16 + idx) * 128;
        const int g1 = ((li >> 2) & 1) << 4;
        f32x4 aRe = {};
        #pragma unroll
        for (int kc = 0; kc < 4; ++kc) {
            const int rb = kc * 16 + Lrow * 4;
            const int rsw = rb ^ (idx << 2) ^ g1;
            short8 bfrag = *(const short8*)&Y[li * 1024 + idx * 64 + rsw];
            const float* wp = wp0 + rb * 2;
            f32x4 u  = *(const f32x4*)wp;
            f32x4 vv = *(const f32x4*)(wp + 4);
            short8 are;
            unsigned* pr = (unsigned*)&are;
            pr[0] = pack2(u[0], -u[1]);   pr[1] = pack2(u[2], -u[3]);
            pr[2] = pack2(vv[0], -vv[1]); pr[3] = pack2(vv[2], -vv[3]);
            aRe = MFMA(are, bfrag, aRe);
        }
        #pragma unroll
        for (int reg = 0; reg < 4; ++reg)
            vRe[reg][li] = aRe[reg];
    }
    #pragma unroll
    for (int reg = 0; reg < 4; ++reg) {
        float* dst = outf + (size_t)(b0 + idx) * 4096 + (size_t)(mw * 16 + Lrow * 4 + reg) * 64 + l0;
        #pragma unroll
        for (int h = 0; h < 4; ++h) {
            f32x4 wv;
            wv[0] = vRe[reg][h*4+0]; wv[1] = vRe[reg][h*4+1];
            wv[2] = vRe[reg][h*4+2]; wv[3] = vRe[reg][h*4+3];
            *(f32x4*)(dst + h * 4) = wv;
        }
    }
}

extern "C" void kernel_launch(void* const* d_in, const int* in_sizes, int n_in,
                              void* d_out, int out_size, void* d_ws, size_t ws_size,
                              hipStream_t stream) {
    const float* x  = (const float*)d_in[0];
    const float* w1 = (const float*)d_in[1];
    const float* w2 = (const float*)d_in[2];
    unsigned int* y1 = (unsigned int*)d_out;
    float* outf = (float*)d_out;

    if (ws_size >= (size_t)2 * 1024 * 1024) {
        unsigned int* w1f = (unsigned int*)d_ws;           // 1 MiB
        unsigned int* w2f = w1f + 262144;                  // 1 MiB
        k_prep   <<<dim3(512),  dim3(256), 0, stream>>>(w1, w2, w1f, w2f);
        k_stage1f<<<dim3(2048), dim3(256), 0, stream>>>(x, (const unsigned short*)w1f, y1);
        k_stage2f<<<dim3(2048), dim3(256), 0, stream>>>(y1, (const unsigned short*)w2f, outf);
    } else {
        k_stage1<<<dim3(2048), dim3(256), 0, stream>>>(x, w1, y1);
        k_stage2<<<dim3(2048), dim3(256), 0, stream>>>(y1, w2, outf);
    }
}